// Round 1
// baseline (668.596 us; speedup 1.0000x reference)
//
#include <hip/hip_runtime.h>

// GCN, 2-layer (16->16 relu, 16->8), DGL GraphConv norm='both', self-loops.
// N = 100000 nodes, E = 3.2M edges. All f32. edge_index passed as int32.

constexpr int F1 = 16;
constexpr int F2 = 8;

__global__ void init_deg_kernel(float* __restrict__ deg_out,
                                float* __restrict__ deg_in, int n) {
    int i = blockIdx.x * 256 + threadIdx.x;
    if (i < n) { deg_out[i] = 1.0f; deg_in[i] = 1.0f; }  // self-loop counts once each
}

__global__ void count_deg_kernel(const int* __restrict__ src,
                                 const int* __restrict__ dst,
                                 float* __restrict__ deg_out,
                                 float* __restrict__ deg_in, int nE) {
    int e = blockIdx.x * 256 + threadIdx.x;
    if (e < nE) {
        atomicAdd(deg_out + src[e], 1.0f);   // exact integer adds in f32 -> deterministic
        atomicAdd(deg_in + dst[e], 1.0f);
    }
}

__global__ void rsqrt_kernel(float* __restrict__ a, float* __restrict__ b, int n) {
    int i = blockIdx.x * 256 + threadIdx.x;
    if (i < n) { a[i] = rsqrtf(a[i]); b[i] = rsqrtf(b[i]); }
}

// h[i,:] = (x[i,:] @ W(16x16)) * norm_src[i]
__global__ void xw16_kernel(const float* __restrict__ x, const float* __restrict__ W,
                            const float* __restrict__ norm_src,
                            float* __restrict__ h, int n) {
    __shared__ float Ws[256];
    int t = threadIdx.x;
    if (t < 256) Ws[t] = W[t];
    __syncthreads();
    int i = blockIdx.x * blockDim.x + t;
    if (i >= n) return;
    float xi[16];
    const float4* xp = reinterpret_cast<const float4*>(x + (size_t)i * 16);
    float4 v;
    v = xp[0]; xi[0]=v.x; xi[1]=v.y; xi[2]=v.z; xi[3]=v.w;
    v = xp[1]; xi[4]=v.x; xi[5]=v.y; xi[6]=v.z; xi[7]=v.w;
    v = xp[2]; xi[8]=v.x; xi[9]=v.y; xi[10]=v.z; xi[11]=v.w;
    v = xp[3]; xi[12]=v.x; xi[13]=v.y; xi[14]=v.z; xi[15]=v.w;
    float ns = norm_src[i];
    float o[16];
#pragma unroll
    for (int j = 0; j < 16; ++j) {
        float acc = 0.f;
#pragma unroll
        for (int k = 0; k < 16; ++k) acc = fmaf(xi[k], Ws[k * 16 + j], acc);
        o[j] = acc * ns;
    }
    float4* hp = reinterpret_cast<float4*>(h + (size_t)i * 16);
    hp[0] = make_float4(o[0], o[1], o[2], o[3]);
    hp[1] = make_float4(o[4], o[5], o[6], o[7]);
    hp[2] = make_float4(o[8], o[9], o[10], o[11]);
    hp[3] = make_float4(o[12], o[13], o[14], o[15]);
}

// h2[i,:] = (h1[i,:] @ W(16x8)) * norm_src[i]
__global__ void xw8_kernel(const float* __restrict__ x, const float* __restrict__ W,
                           const float* __restrict__ norm_src,
                           float* __restrict__ h, int n) {
    __shared__ float Ws[128];
    int t = threadIdx.x;
    if (t < 128) Ws[t] = W[t];
    __syncthreads();
    int i = blockIdx.x * blockDim.x + t;
    if (i >= n) return;
    float xi[16];
    const float4* xp = reinterpret_cast<const float4*>(x + (size_t)i * 16);
    float4 v;
    v = xp[0]; xi[0]=v.x; xi[1]=v.y; xi[2]=v.z; xi[3]=v.w;
    v = xp[1]; xi[4]=v.x; xi[5]=v.y; xi[6]=v.z; xi[7]=v.w;
    v = xp[2]; xi[8]=v.x; xi[9]=v.y; xi[10]=v.z; xi[11]=v.w;
    v = xp[3]; xi[12]=v.x; xi[13]=v.y; xi[14]=v.z; xi[15]=v.w;
    float ns = norm_src[i];
    float o[8];
#pragma unroll
    for (int j = 0; j < 8; ++j) {
        float acc = 0.f;
#pragma unroll
        for (int k = 0; k < 16; ++k) acc = fmaf(xi[k], Ws[k * 8 + j], acc);
        o[j] = acc * ns;
    }
    float4* hp = reinterpret_cast<float4*>(h + (size_t)i * 8);
    hp[0] = make_float4(o[0], o[1], o[2], o[3]);
    hp[1] = make_float4(o[4], o[5], o[6], o[7]);
}

// agg[dst[e], f] += h[src[e], f], one thread per (edge, feature)
template <int F>
__global__ void scatter_kernel(const int* __restrict__ src, const int* __restrict__ dst,
                               const float* __restrict__ h, float* __restrict__ agg,
                               int nE) {
    long long t = (long long)blockIdx.x * blockDim.x + threadIdx.x;
    if (t >= (long long)nE * F) return;
    int e = (int)(t >> (F == 16 ? 4 : 3));
    int f = (int)(t & (F - 1));
    int s = src[e];
    int d = dst[e];
    atomicAdd(agg + (size_t)d * F + f, h[(size_t)s * F + f]);
}

// out = ((agg + h_self) * norm_dst + b), optional relu. Safe in-place (out==agg).
template <int F, bool RELU>
__global__ void combine_kernel(const float* __restrict__ agg, const float* __restrict__ h,
                               const float* __restrict__ norm_dst,
                               const float* __restrict__ b,
                               float* __restrict__ out, int n) {
    int t = blockIdx.x * 256 + threadIdx.x;
    if (t >= n * F) return;
    int i = t / F;
    int f = t % F;  // F power of 2 -> compiler uses shifts/masks
    float v = (agg[t] + h[t]) * norm_dst[i] + b[f];
    if (RELU) v = fmaxf(v, 0.f);
    out[t] = v;
}

extern "C" void kernel_launch(void* const* d_in, const int* in_sizes, int n_in,
                              void* d_out, int out_size, void* d_ws, size_t ws_size,
                              hipStream_t stream) {
    const float* x  = (const float*)d_in[0];
    const float* W1 = (const float*)d_in[1];
    const float* b1 = (const float*)d_in[2];
    const float* W2 = (const float*)d_in[3];
    const float* b2 = (const float*)d_in[4];
    const int*   ei = (const int*)d_in[5];

    const int n  = in_sizes[0] / F1;   // 100000
    const int nE = in_sizes[5] / 2;    // 3200000
    const int* src = ei;
    const int* dst = ei + nE;

    // workspace layout (aligned to 256B)
    size_t na = ((size_t)n + 63) & ~(size_t)63;
    float* norm_src = (float*)d_ws;          // [n] degrees -> rsqrt
    float* norm_dst = norm_src + na;         // [n]
    float* bufA     = norm_dst + na;         // [n*16] h (layer1), then h2 (layer2)
    float* bufB     = bufA + na * F1;        // [n*16] agg1 -> h1 (in place), then agg2

    const int B = 256;
    dim3 blk(B);
    int gN   = (n + B - 1) / B;
    int gE   = (nE + B - 1) / B;
    int gNF1 = (n * F1 + B - 1) / B;
    int gNF2 = (n * F2 + B - 1) / B;
    int gEF1 = (int)(((long long)nE * F1 + B - 1) / B);
    int gEF2 = (int)(((long long)nE * F2 + B - 1) / B);

    // degrees + norms
    init_deg_kernel<<<gN, blk, 0, stream>>>(norm_src, norm_dst, n);
    count_deg_kernel<<<gE, blk, 0, stream>>>(src, dst, norm_src, norm_dst, nE);
    rsqrt_kernel<<<gN, blk, 0, stream>>>(norm_src, norm_dst, n);

    // layer 1
    xw16_kernel<<<gN, blk, 0, stream>>>(x, W1, norm_src, bufA, n);
    hipMemsetAsync(bufB, 0, (size_t)n * F1 * sizeof(float), stream);
    scatter_kernel<F1><<<gEF1, blk, 0, stream>>>(src, dst, bufA, bufB, nE);
    combine_kernel<F1, true><<<gNF1, blk, 0, stream>>>(bufB, bufA, norm_dst, b1, bufB, n);

    // layer 2 (h1 = bufB, h2 -> bufA, agg2 -> bufB reused)
    xw8_kernel<<<gN, blk, 0, stream>>>(bufB, W2, norm_src, bufA, n);
    hipMemsetAsync(bufB, 0, (size_t)n * F2 * sizeof(float), stream);
    scatter_kernel<F2><<<gEF2, blk, 0, stream>>>(src, dst, bufA, bufB, nE);
    combine_kernel<F2, false><<<gNF2, blk, 0, stream>>>(bufB, bufA, norm_dst, b2,
                                                        (float*)d_out, n);
}

// Round 2
// 409.920 us; speedup vs baseline: 1.6310x; 1.6310x over previous
//
#include <hip/hip_runtime.h>

// GCN, 2-layer (16->16 relu, 16->8), DGL GraphConv norm='both', self-loops.
// N = 100000 nodes, E = 3.2M edges. All f32. edge_index passed as int32.

constexpr int F1 = 16;
constexpr int F2 = 8;
constexpr int NB_HIST = 128;     // histogram blocks (partials overlay bufA/bufB)
constexpr int HIST_N  = 100000;  // node count this path is specialized for
constexpr int HIST_U32 = HIST_N / 4;  // 25000 u32 = 100000 packed u8 bins

// ---- fast degree path: LDS packed-u8 histogram + byte-sum merge ----

__global__ void __launch_bounds__(256) hist_kernel(const int* __restrict__ idx,
                                                   unsigned* __restrict__ partial,
                                                   int nE, int per_block) {
    __shared__ unsigned h[HIST_U32];
    for (int i = threadIdx.x; i < HIST_U32; i += 256) h[i] = 0u;
    __syncthreads();
    const int beg = blockIdx.x * per_block;
    const int end = min(nE, beg + per_block);
    for (int base = beg; base < end; base += 256 * 4) {
        int i = base + threadIdx.x * 4;
        if (i + 3 < end) {
            int4 v = *reinterpret_cast<const int4*>(idx + i);
            atomicAdd(&h[v.x >> 2], 1u << ((v.x & 3) << 3));
            atomicAdd(&h[v.y >> 2], 1u << ((v.y & 3) << 3));
            atomicAdd(&h[v.z >> 2], 1u << ((v.z & 3) << 3));
            atomicAdd(&h[v.w >> 2], 1u << ((v.w & 3) << 3));
        } else {
#pragma unroll
            for (int k = 0; k < 4; ++k)
                if (i + k < end) {
                    int v = idx[i + k];
                    atomicAdd(&h[v >> 2], 1u << ((v & 3) << 3));
                }
        }
    }
    __syncthreads();
    unsigned* out = partial + (size_t)blockIdx.x * HIST_U32;
    for (int i = threadIdx.x; i < HIST_U32; i += 256) out[i] = h[i];
}

// norm[i] = rsqrt(1 + sum_b partial_bytes[b][i])   (self-loop folded in)
__global__ void __launch_bounds__(256) merge_norm_kernel(const unsigned* __restrict__ partial,
                                                         float* __restrict__ norm) {
    int t = blockIdx.x * 256 + threadIdx.x;
    if (t >= HIST_U32) return;
    unsigned s0 = 0, s1 = 0, s2 = 0, s3 = 0;
    const unsigned* p = partial + t;
    for (int b = 0; b < NB_HIST; ++b) {
        unsigned v = p[(size_t)b * HIST_U32];
        s0 += v & 0xffu; s1 += (v >> 8) & 0xffu;
        s2 += (v >> 16) & 0xffu; s3 += v >> 24;
    }
    float4 o = make_float4(rsqrtf(1.f + (float)s0), rsqrtf(1.f + (float)s1),
                           rsqrtf(1.f + (float)s2), rsqrtf(1.f + (float)s3));
    *reinterpret_cast<float4*>(norm + (size_t)t * 4) = o;
}

// ---- fallback degree path (n != 100000): scattered atomics ----

__global__ void init_deg_kernel(float* __restrict__ a, float* __restrict__ b, int n) {
    int i = blockIdx.x * 256 + threadIdx.x;
    if (i < n) { a[i] = 1.0f; b[i] = 1.0f; }
}
__global__ void count_deg_kernel(const int* __restrict__ src, const int* __restrict__ dst,
                                 float* __restrict__ dego, float* __restrict__ degi, int nE) {
    int e = blockIdx.x * 256 + threadIdx.x;
    if (e < nE) { atomicAdd(dego + src[e], 1.0f); atomicAdd(degi + dst[e], 1.0f); }
}
__global__ void rsqrt_kernel(float* __restrict__ a, float* __restrict__ b, int n) {
    int i = blockIdx.x * 256 + threadIdx.x;
    if (i < n) { a[i] = rsqrtf(a[i]); b[i] = rsqrtf(b[i]); }
}

// ---- dense transforms ----

// h[i,:] = (x[i,:] @ W(16x16)) * norm_src[i]
__global__ void xw16_kernel(const float* __restrict__ x, const float* __restrict__ W,
                            const float* __restrict__ norm_src,
                            float* __restrict__ h, int n) {
    __shared__ float Ws[256];
    int t = threadIdx.x;
    if (t < 256) Ws[t] = W[t];
    __syncthreads();
    int i = blockIdx.x * blockDim.x + t;
    if (i >= n) return;
    float xi[16];
    const float4* xp = reinterpret_cast<const float4*>(x + (size_t)i * 16);
    float4 v;
    v = xp[0]; xi[0]=v.x; xi[1]=v.y; xi[2]=v.z; xi[3]=v.w;
    v = xp[1]; xi[4]=v.x; xi[5]=v.y; xi[6]=v.z; xi[7]=v.w;
    v = xp[2]; xi[8]=v.x; xi[9]=v.y; xi[10]=v.z; xi[11]=v.w;
    v = xp[3]; xi[12]=v.x; xi[13]=v.y; xi[14]=v.z; xi[15]=v.w;
    float ns = norm_src[i];
    float o[16];
#pragma unroll
    for (int j = 0; j < 16; ++j) {
        float acc = 0.f;
#pragma unroll
        for (int k = 0; k < 16; ++k) acc = fmaf(xi[k], Ws[k * 16 + j], acc);
        o[j] = acc * ns;
    }
    float4* hp = reinterpret_cast<float4*>(h + (size_t)i * 16);
    hp[0] = make_float4(o[0], o[1], o[2], o[3]);
    hp[1] = make_float4(o[4], o[5], o[6], o[7]);
    hp[2] = make_float4(o[8], o[9], o[10], o[11]);
    hp[3] = make_float4(o[12], o[13], o[14], o[15]);
}

// h2[i,:] = (h1[i,:] @ W(16x8)) * norm_src[i]
__global__ void xw8_kernel(const float* __restrict__ x, const float* __restrict__ W,
                           const float* __restrict__ norm_src,
                           float* __restrict__ h, int n) {
    __shared__ float Ws[128];
    int t = threadIdx.x;
    if (t < 128) Ws[t] = W[t];
    __syncthreads();
    int i = blockIdx.x * blockDim.x + t;
    if (i >= n) return;
    float xi[16];
    const float4* xp = reinterpret_cast<const float4*>(x + (size_t)i * 16);
    float4 v;
    v = xp[0]; xi[0]=v.x; xi[1]=v.y; xi[2]=v.z; xi[3]=v.w;
    v = xp[1]; xi[4]=v.x; xi[5]=v.y; xi[6]=v.z; xi[7]=v.w;
    v = xp[2]; xi[8]=v.x; xi[9]=v.y; xi[10]=v.z; xi[11]=v.w;
    v = xp[3]; xi[12]=v.x; xi[13]=v.y; xi[14]=v.z; xi[15]=v.w;
    float ns = norm_src[i];
    float o[8];
#pragma unroll
    for (int j = 0; j < 8; ++j) {
        float acc = 0.f;
#pragma unroll
        for (int k = 0; k < 16; ++k) acc = fmaf(xi[k], Ws[k * 8 + j], acc);
        o[j] = acc * ns;
    }
    float4* hp = reinterpret_cast<float4*>(h + (size_t)i * 8);
    hp[0] = make_float4(o[0], o[1], o[2], o[3]);
    hp[1] = make_float4(o[4], o[5], o[6], o[7]);
}

// agg[dst[e], f] += h[src[e], f], one thread per (edge, feature)
template <int F>
__global__ void scatter_kernel(const int* __restrict__ src, const int* __restrict__ dst,
                               const float* __restrict__ h, float* __restrict__ agg,
                               int nE) {
    long long t = (long long)blockIdx.x * blockDim.x + threadIdx.x;
    if (t >= (long long)nE * F) return;
    int e = (int)(t >> (F == 16 ? 4 : 3));
    int f = (int)(t & (F - 1));
    int s = src[e];
    int d = dst[e];
    atomicAdd(agg + (size_t)d * F + f, h[(size_t)s * F + f]);
}

// out = ((agg + h_self) * norm_dst + b), optional relu. Safe in-place (out==agg).
template <int F, bool RELU>
__global__ void combine_kernel(const float* __restrict__ agg, const float* __restrict__ h,
                               const float* __restrict__ norm_dst,
                               const float* __restrict__ b,
                               float* __restrict__ out, int n) {
    int t = blockIdx.x * 256 + threadIdx.x;
    if (t >= n * F) return;
    int i = t / F;
    int f = t % F;
    float v = (agg[t] + h[t]) * norm_dst[i] + b[f];
    if (RELU) v = fmaxf(v, 0.f);
    out[t] = v;
}

extern "C" void kernel_launch(void* const* d_in, const int* in_sizes, int n_in,
                              void* d_out, int out_size, void* d_ws, size_t ws_size,
                              hipStream_t stream) {
    const float* x  = (const float*)d_in[0];
    const float* W1 = (const float*)d_in[1];
    const float* b1 = (const float*)d_in[2];
    const float* W2 = (const float*)d_in[3];
    const float* b2 = (const float*)d_in[4];
    const int*   ei = (const int*)d_in[5];

    const int n  = in_sizes[0] / F1;   // 100000
    const int nE = in_sizes[5] / 2;    // 3200000
    const int* src = ei;
    const int* dst = ei + nE;

    // workspace layout (64-elem aligned)
    size_t na = ((size_t)n + 63) & ~(size_t)63;
    float* norm_src = (float*)d_ws;          // [n]
    float* norm_dst = norm_src + na;         // [n]
    float* bufA     = norm_dst + na;         // [n*16]
    float* bufB     = bufA + na * F1;        // [n*16]
    // histogram partials overlay bufA/bufB (consumed before bufA first written)
    unsigned* partial = (unsigned*)bufA;     // NB_HIST * HIST_U32 u32 = 12.8 MB

    const int B = 256;
    dim3 blk(B);
    int gN   = (n + B - 1) / B;
    int gNF1 = (n * F1 + B - 1) / B;
    int gNF2 = (n * F2 + B - 1) / B;
    int gEF1 = (int)(((long long)nE * F1 + B - 1) / B);
    int gEF2 = (int)(((long long)nE * F2 + B - 1) / B);

    if (n == HIST_N) {
        int per_block = (nE + NB_HIST - 1) / NB_HIST;
        int gM = (HIST_U32 + B - 1) / B;
        hist_kernel<<<NB_HIST, blk, 0, stream>>>(src, partial, nE, per_block);
        merge_norm_kernel<<<gM, blk, 0, stream>>>(partial, norm_src);
        hist_kernel<<<NB_HIST, blk, 0, stream>>>(dst, partial, nE, per_block);
        merge_norm_kernel<<<gM, blk, 0, stream>>>(partial, norm_dst);
    } else {
        int gE = (nE + B - 1) / B;
        init_deg_kernel<<<gN, blk, 0, stream>>>(norm_src, norm_dst, n);
        count_deg_kernel<<<gE, blk, 0, stream>>>(src, dst, norm_src, norm_dst, nE);
        rsqrt_kernel<<<gN, blk, 0, stream>>>(norm_src, norm_dst, n);
    }

    // layer 1
    xw16_kernel<<<gN, blk, 0, stream>>>(x, W1, norm_src, bufA, n);
    hipMemsetAsync(bufB, 0, (size_t)n * F1 * sizeof(float), stream);
    scatter_kernel<F1><<<gEF1, blk, 0, stream>>>(src, dst, bufA, bufB, nE);
    combine_kernel<F1, true><<<gNF1, blk, 0, stream>>>(bufB, bufA, norm_dst, b1, bufB, n);

    // layer 2 (h1 = bufB, h2 -> bufA, agg2 -> bufB reused)
    xw8_kernel<<<gN, blk, 0, stream>>>(bufB, W2, norm_src, bufA, n);
    hipMemsetAsync(bufB, 0, (size_t)n * F2 * sizeof(float), stream);
    scatter_kernel<F2><<<gEF2, blk, 0, stream>>>(src, dst, bufA, bufB, nE);
    combine_kernel<F2, false><<<gNF2, blk, 0, stream>>>(bufB, bufA, norm_dst, b2,
                                                        (float*)d_out, n);
}